// Round 23
// baseline (58.669 us; speedup 1.0000x reference)
//
#include <hip/hip_runtime.h>
#include <math.h>

// ---------------------------------------------------------------------------
// EEGGENET fused implementation (round 23 = r22 MFMA mix, 32-output tiles,
// 1024-thread blocks).
// Shapes: B=64, C=64, T=1000, F1=8, D=2, F2=16, KLEN=64, NCLS=4.
//
// Algebra: graph conv + spatial conv + BN1 + BN2 fold into Wf[48][64]; channel
// contraction commutes with the temporal conv. Mix P[48][320] = W x X on
// matrix cores via bf16 hi/lo split (r19: absmax 2.4e-7; r21/r22: 64-VGPR
// fit, no spill; r22 total 39.8us).
// This round: tile = 32 pool outputs (320-col window, 20 col-tiles),
// 256 blocks x 1024 threads = 1 block/CU, 16 waves/CU (same residency as
// r22, half the per-block fixed costs, halo 1.5x -> 1.25x).
// Mix pass A = 16 waves x tiles 0-15; pass B = waves 0-3 x tiles 16-19.
// FIR: 1536 tasks over 1024 threads (1.5 passes).
// ---------------------------------------------------------------------------

#define EPS_BN 1e-3f

// ws layout (floats / u32)
#define WHL_OFF  0        // u32[48 oc][64 j]: (bf16hi<<16)|bf16lo of folded W
#define BIAS_OFF 3072     // bias[48]
#define A3_OFF   3120     // a3[16]
#define C3_OFF   3136     // c3[16]
#define CLS_OFF  3152     // renormed cls_w [4][240]
#define OUT1_OFF 4176     // pooled stage-1 output [64][48][125]

// stage1 smem (floats): 16144 = 64576 B; 1024 thr, 1 block/CU
#define S_PS   0          // ps[48][324]
#define S_TW   15552      // twp[8 f][68]
#define S_BIAS 16096      // [48]
#define S1_TOT 16144

typedef short bf16x8 __attribute__((ext_vector_type(8)));
typedef float f32x4 __attribute__((ext_vector_type(4)));

__device__ __forceinline__ unsigned short bf16_rne(float f) {
    unsigned u = __float_as_uint(f);
    return (unsigned short)((u + 0x7fffu + ((u >> 16) & 1u)) >> 16);
}

// ---------------------------------------------------------------------------
__global__ __launch_bounds__(256) void eeg_setup_kernel(
    const float* __restrict__ g1, const float* __restrict__ b1,
    const float* __restrict__ m1, const float* __restrict__ v1,
    const float* __restrict__ e1, const float* __restrict__ e2,
    const float* __restrict__ sw,
    const float* __restrict__ g2, const float* __restrict__ b2,
    const float* __restrict__ m2, const float* __restrict__ v2,
    const float* __restrict__ g3, const float* __restrict__ b3,
    const float* __restrict__ m3, const float* __restrict__ v3,
    const float* __restrict__ clsw, float* __restrict__ ws)
{
    const int tid = threadIdx.x;
    const int blk = blockIdx.x;

    if (blk < 48) {
        const int oc = blk;
        const int k = oc >> 4;          // hop: 0=identity, 1=A1, 2=A2
        __shared__ float A[64][65];
        __shared__ float rsl[64];
        __shared__ float swl[64];
        __shared__ float sred;

        if (k > 0) {
            const float* e = (k == 1) ? e1 : e2;
            for (int idx = tid; idx < 4096; idx += 256) {
                int i = idx >> 6, j = idx & 63;
                float v;
                if (i == j) v = 1.f;
                else {
                    int ii = i > j ? i : j, jj = i > j ? j : i;
                    v = e[ii * (ii - 1) / 2 + jj];
                }
                A[i][j] = v;
            }
        }
        if (tid < 64) swl[tid] = sw[oc * 64 + tid];
        __syncthreads();
        if (tid < 64) {
            if (k > 0) {
                float s = 0.f;
                for (int j = 0; j < 64; ++j) s += A[tid][j];
                rsl[tid] = 1.f / s;
            }
            float nv = swl[tid] * swl[tid];
            for (int off = 32; off; off >>= 1) nv += __shfl_down(nv, off);
            if (tid == 0) sred = nv;
        }
        __syncthreads();
        if (tid < 64) {
            const int j = tid;
            const float sn = fminf(1.f, 1.f / fmaxf(sqrtf(sred), 1e-7f));
            float w;
            if (k == 0) w = swl[j];
            else {
                float acc = 0.f;
                for (int c = 0; c < 64; ++c) acc += swl[c] * rsl[c] * A[c][j];
                w = acc;
            }
            w *= sn;
            const int f = (oc >> 1) & 7;
            const float a1 = g1[f] * rsqrtf(v1[f] + EPS_BN);
            const float a2 = g2[oc] * rsqrtf(v2[oc] + EPS_BN);
            const float wv = a2 * a1 * w;
            // bf16 hi/lo split, packed
            const unsigned short h = bf16_rne(wv);
            const float hf = __uint_as_float(((unsigned)h) << 16);
            const unsigned short lo = bf16_rne(wv - hf);
            ((unsigned*)ws)[WHL_OFF + oc * 64 + j] = (((unsigned)h) << 16) | lo;
            float S = w;
            for (int off = 32; off; off >>= 1) S += __shfl_down(S, off);
            if (tid == 0) {
                const float c1 = b1[f] - m1[f] * a1;
                const float c2 = b2[oc] - m2[oc] * a2;
                ws[BIAS_OFF + oc] = a2 * c1 * S + c2;
            }
        }
    } else {
        __shared__ float csc[4];
        if (tid < 16) {
            const float a3 = g3[tid] * rsqrtf(v3[tid] + EPS_BN);
            ws[A3_OFF + tid] = a3;
            ws[C3_OFF + tid] = b3[tid] - m3[tid] * a3;
        }
        {   // classifier renorm (maxnorm 0.25): row = wave
            const int row = tid >> 6, lane = tid & 63;
            float p = 0.f;
            if (row < 4)
                for (int idx = lane; idx < 240; idx += 64) {
                    float w = clsw[row * 240 + idx];
                    p += w * w;
                }
            for (int off = 32; off; off >>= 1) p += __shfl_down(p, off);
            if (row < 4 && lane == 0)
                csc[row] = fminf(1.f, 0.25f / fmaxf(sqrtf(p), 1e-7f));
        }
        __syncthreads();
        for (int idx = tid; idx < 960; idx += 256)
            ws[CLS_OFF + idx] = clsw[idx] * csc[idx / 240];
    }
}

// ---------------------------------------------------------------------------
// One rt body: load A frags (inside, pressure-bounded, L1-hot), 3 MFMAs.
#define RT_BODY(rt)                                                          \
    {                                                                        \
        const unsigned* ap = whl + (16 * (rt) + l15) * 64 + 32 * ks + 8 * lg;\
        const uint4 aw0 = *(const uint4*)ap;                                 \
        const uint4 aw1 = *(const uint4*)(ap + 4);                           \
        bf16x8 ah, al;                                                       \
        const unsigned* av0 = (const unsigned*)&aw0;                         \
        const unsigned* av1 = (const unsigned*)&aw1;                         \
        _Pragma("unroll")                                                    \
        for (int i = 0; i < 4; ++i) {                                        \
            ah[i] = (short)(av0[i] >> 16);                                   \
            al[i] = (short)(av0[i] & 0xffffu);                               \
            ah[i + 4] = (short)(av1[i] >> 16);                               \
            al[i + 4] = (short)(av1[i] & 0xffffu);                           \
        }                                                                    \
        acc[rt] = __builtin_amdgcn_mfma_f32_16x16x32_bf16(ah, bh, acc[rt], 0, 0, 0); \
        acc[rt] = __builtin_amdgcn_mfma_f32_16x16x32_bf16(ah, bl, acc[rt], 0, 0, 0); \
        acc[rt] = __builtin_amdgcn_mfma_f32_16x16x32_bf16(al, bh, acc[rt], 0, 0, 0); \
    }

// mix one 16-col tile (tilec = column tile index 0..19) into ps
__device__ __forceinline__ void mix_tile(
    const float* __restrict__ x, const unsigned* __restrict__ whl,
    float* __restrict__ smem, int b, int u0, int tilec, int l15, int lg)
{
    f32x4 acc[3];
#pragma unroll
    for (int rt = 0; rt < 3; ++rt) acc[rt] = (f32x4){0.f, 0.f, 0.f, 0.f};

    const int col = 16 * tilec + l15;
    const int u = u0 + col;
    const bool valid = (u >= 0) && (u < 1000);
    const float* xp = x + (size_t)b * 64000 + (valid ? u : 0);

#pragma unroll
    for (int ks = 0; ks < 2; ++ks) {
        float xf[8];
#pragma unroll
        for (int i = 0; i < 8; ++i) {
            const int j = 32 * ks + 8 * lg + i;
            xf[i] = valid ? xp[j * 1000] : 0.f;
        }
        bf16x8 bh, bl;
#pragma unroll
        for (int i = 0; i < 8; ++i) {
            const float f = xf[i];
            const unsigned short h = bf16_rne(f);
            const float hf = __uint_as_float(((unsigned)h) << 16);
            const unsigned short lo = bf16_rne(f - hf);
            bh[i] = (short)h;
            bl[i] = (short)lo;
        }
        RT_BODY(0)
        RT_BODY(1)
        RT_BODY(2)
    }
#pragma unroll
    for (int rt = 0; rt < 3; ++rt)
#pragma unroll
        for (int r = 0; r < 4; ++r)
            smem[S_PS + (16 * rt + 4 * lg + r) * 324 + col] = acc[rt][r];
}

__global__ __launch_bounds__(1024) void eeg_stage1_kernel(
    const float* __restrict__ x, const float* __restrict__ tw,
    const float* __restrict__ wcon, float* __restrict__ out1)
{
    __shared__ float smem[S1_TOT];
    const int tid = threadIdx.x;
    const int lane = tid & 63;
    const int wv = tid >> 6;                 // wave 0..15
    const int l15 = lane & 15;
    const int lg = lane >> 4;                // 0..3
    // XCD-aware swizzle (256 % 8 == 0, bijective)
    const int newid = (blockIdx.x & 7) * 32 + (blockIdx.x >> 3);
    const int b = newid >> 2;
    const int tile = newid & 3;              // 0..3
    const int o0 = tile * 32;
    const int u0 = 256 * tile - 32;

    // stage tw (stride 68, conflict-free) + bias
    if (tid < 512)
        smem[S_TW + (tid >> 6) * 68 + (tid & 63)] = tw[tid];
    if (tid < 48) smem[S_BIAS + tid] = wcon[BIAS_OFF + tid];

    const unsigned* whl = (const unsigned*)wcon;   // WHL_OFF = 0

    // mix pass A: tiles 0..15 (all waves); pass B: tiles 16..19 (waves 0..3)
    mix_tile(x, whl, smem, b, u0, wv, l15, lg);
    if (wv < 4) mix_tile(x, whl, smem, b, u0, 16 + wv, l15, lg);
    __syncthreads();   // ps complete (cross-wave) + tw/bias staged

    // ---- FIR(64) + bias + ELU + pool8: 1536 tasks over 1024 threads ----
#pragma unroll
    for (int p = 0; p < 2; ++p) {
        const int task = p * 1024 + tid;
        if (task < 1536) {
            const int oc = task >> 5;
            const int o = task & 31;
            const int oo = o0 + o;
            if (oo < 125) {
                const int f = (oc >> 1) & 7;
                const float* row = smem + S_PS + oc * 324 + o * 8;
                float win[72];
#pragma unroll
                for (int kk = 0; kk < 18; ++kk) {
                    const float4 t = *(const float4*)(row + 4 * kk);
                    win[4 * kk + 0] = t.x; win[4 * kk + 1] = t.y;
                    win[4 * kk + 2] = t.z; win[4 * kk + 3] = t.w;
                }
                const float bs = smem[S_BIAS + oc];
                const float* twf = smem + S_TW + f * 68;
                float accv[8];
#pragma unroll
                for (int r = 0; r < 8; ++r) accv[r] = bs;
#pragma unroll
                for (int q0 = 0; q0 < 64; q0 += 8) {
                    float tws[8];
                    const float4 ta = *(const float4*)(twf + q0);
                    const float4 tb = *(const float4*)(twf + q0 + 4);
                    tws[0] = ta.x; tws[1] = ta.y; tws[2] = ta.z; tws[3] = ta.w;
                    tws[4] = tb.x; tws[5] = tb.y; tws[6] = tb.z; tws[7] = tb.w;
#pragma unroll
                    for (int q = 0; q < 8; ++q) {
#pragma unroll
                        for (int r = 0; r < 8; ++r)
                            accv[r] += tws[q] * win[q0 + q + r];
                    }
                }
                float s = 0.f;
#pragma unroll
                for (int r = 0; r < 8; ++r) {
                    const float v = accv[r];
                    s += (v > 0.f) ? v : expm1f(v);
                }
                out1[((size_t)b * 48 + oc) * 125 + oo] = s * 0.125f;
            }
        }
    }
}

// ---------------------------------------------------------------------------
// Stage 2: per batch, 512 threads. dw conv(16,pad8) -> pw 48->16 -> BN3+ELU
// -> pool8 -> classifier. 64 blocks, float4 LDS staging.
// ---------------------------------------------------------------------------
#define SB_P1   0        // [48][125]  (reused for QQ [16][126])
#define SB_DWO  6000     // [48][126]  (reused for pooled [16][15])
#define SB_DWL  12048    // [48][16]
#define SB_PWL  12816    // [16][48]
#define SB_CLS  13584    // [4][240]
#define SB_A3   14544    // [16]
#define SB_C3   14560    // [16]
#define SB_TOT  14576

__global__ __launch_bounds__(512) void eeg_stage2_kernel(
    const float* __restrict__ ws, const float* __restrict__ dww,
    const float* __restrict__ pww, const float* __restrict__ clsb,
    float* __restrict__ out)
{
    __shared__ float sb[SB_TOT];
    const int tid = threadIdx.x;
    const int b = blockIdx.x;
    const float* o1 = ws + OUT1_OFF + (size_t)b * 6000;

    for (int i = tid; i < 1500; i += 512)
        ((float4*)(sb + SB_P1))[i] = ((const float4*)o1)[i];
    if (tid < 192) ((float4*)(sb + SB_DWL))[tid] = ((const float4*)dww)[tid];
    if (tid < 192) ((float4*)(sb + SB_PWL))[tid] = ((const float4*)pww)[tid];
    if (tid < 240) ((float4*)(sb + SB_CLS))[tid] = ((const float4*)(ws + CLS_OFF))[tid];
    if (tid < 16) { sb[SB_A3 + tid] = ws[A3_OFF + tid]; sb[SB_C3 + tid] = ws[C3_OFF + tid]; }
    __syncthreads();

    // depthwise conv: K=16, pad 8, T 125 -> 126
    for (int idx = tid; idx < 48 * 126; idx += 512) {
        int ci = idx / 126, t = idx - ci * 126;
        float acc = 0.f;
#pragma unroll
        for (int r = 0; r < 16; ++r) {
            int tt = t - 8 + r;
            float xv = (tt >= 0 && tt < 125) ? sb[SB_P1 + ci * 125 + tt] : 0.f;
            acc += sb[SB_DWL + ci * 16 + r] * xv;
        }
        sb[SB_DWO + idx] = acc;
    }
    __syncthreads();
    // pointwise 48->16 + BN3 + ELU  (overwrites P1 region, disjoint from DWO)
    for (int idx = tid; idx < 16 * 126; idx += 512) {
        int co = idx / 126, t = idx - co * 126;
        float acc = 0.f;
#pragma unroll
        for (int ci = 0; ci < 48; ++ci)
            acc += sb[SB_PWL + co * 48 + ci] * sb[SB_DWO + ci * 126 + t];
        float v = sb[SB_A3 + co] * acc + sb[SB_C3 + co];
        sb[SB_P1 + idx] = (v > 0.f) ? v : expm1f(v);
    }
    __syncthreads();
    // pool8: 126 -> 15 (overwrites DWO region)
    if (tid < 240) {
        int co = tid / 15, v = tid - co * 15;
        float s = 0.f;
#pragma unroll
        for (int r = 0; r < 8; ++r) s += sb[SB_P1 + co * 126 + v * 8 + r];
        sb[SB_DWO + tid] = s * 0.125f;
    }
    __syncthreads();
    // classifier: wave w (<4) -> class w, 64-lane reduce over 240
    {
        const int wv = tid >> 6, lane = tid & 63;
        if (wv < 4) {
            float p = 0.f;
            for (int j2 = lane; j2 < 240; j2 += 64)
                p += sb[SB_CLS + wv * 240 + j2] * sb[SB_DWO + j2];
            for (int off = 32; off; off >>= 1) p += __shfl_down(p, off);
            if (lane == 0) out[(size_t)b * 4 + wv] = p + clsb[wv];
        }
    }
}

extern "C" void kernel_launch(void* const* d_in, const int* in_sizes, int n_in,
                              void* d_out, int out_size, void* d_ws, size_t ws_size,
                              hipStream_t stream) {
    const float* x    = (const float*)d_in[0];
    const float* tw   = (const float*)d_in[1];
    const float* g1   = (const float*)d_in[2];
    const float* b1   = (const float*)d_in[3];
    const float* m1   = (const float*)d_in[4];
    const float* v1   = (const float*)d_in[5];
    const float* e1   = (const float*)d_in[6];
    const float* e2   = (const float*)d_in[7];
    const float* sw   = (const float*)d_in[8];
    const float* g2   = (const float*)d_in[9];
    const float* b2   = (const float*)d_in[10];
    const float* m2   = (const float*)d_in[11];
    const float* v2   = (const float*)d_in[12];
    const float* dww  = (const float*)d_in[13];
    const float* pww  = (const float*)d_in[14];
    const float* g3   = (const float*)d_in[15];
    const float* b3   = (const float*)d_in[16];
    const float* m3   = (const float*)d_in[17];
    const float* v3   = (const float*)d_in[18];
    const float* clsw = (const float*)d_in[19];
    const float* clsb = (const float*)d_in[20];
    float* ws = (float*)d_ws;
    float* out = (float*)d_out;

    eeg_setup_kernel<<<49, 256, 0, stream>>>(g1, b1, m1, v1, e1, e2, sw,
                                             g2, b2, m2, v2, g3, b3, m3, v3,
                                             clsw, ws);
    eeg_stage1_kernel<<<256, 1024, 0, stream>>>(x, tw, ws, ws + OUT1_OFF);
    eeg_stage2_kernel<<<64, 512, 0, stream>>>(ws, dww, pww, clsb, out);
}

// Round 24
// 41.030 us; speedup vs baseline: 1.4299x; 1.4299x over previous
//
#include <hip/hip_runtime.h>
#include <math.h>

// ---------------------------------------------------------------------------
// EEGGENET fused implementation (round 24 = r22 MFMA mix, 768-thread blocks:
// 12 waves = 12 col-tiles in ONE mix pass; FIR = exactly 1 task/thread).
// Shapes: B=64, C=64, T=1000, F1=8, D=2, F2=16, KLEN=64, NCLS=4.
//
// Algebra: graph conv + spatial conv + BN1 + BN2 fold into Wf[48][64]; channel
// contraction commutes with the temporal conv. Mix P[48][192] = W x X on
// matrix cores via bf16 hi/lo split (r19: absmax 2.4e-7; r21/r22: 64-VGPR
// fit, no spill; r22 total 39.8us best).
// r23 lesson: 1 block/CU kills cross-block overlap at the barrier; tile=16
// with 2 blocks/CU is the sweet spot. This round removes r22's two idle-wave
// defects at constant tile/LDS: pass-B serial tail (4 tiles on 4 of 8 waves)
// and FIR's 1.5-pass mapping.
// ---------------------------------------------------------------------------

#define EPS_BN 1e-3f

// ws layout (floats / u32)
#define WHL_OFF  0        // u32[48 oc][64 j]: (bf16hi<<16)|bf16lo of folded W
#define BIAS_OFF 3072     // bias[48]
#define A3_OFF   3120     // a3[16]
#define C3_OFF   3136     // c3[16]
#define CLS_OFF  3152     // renormed cls_w [4][240]
#define OUT1_OFF 4176     // pooled stage-1 output [64][48][125]

// stage1 smem (floats): 10000 = 40000 B; 768 thr -> 2 blocks/CU (1536 thr,
// 80 KB LDS per CU), grid 512 = one balanced round.
#define S_PS   0          // ps[48][196]
#define S_TW   9408       // twp[8 f][68]
#define S_BIAS 9952       // [48]
#define S1_TOT 10000

typedef short bf16x8 __attribute__((ext_vector_type(8)));
typedef float f32x4 __attribute__((ext_vector_type(4)));

__device__ __forceinline__ unsigned short bf16_rne(float f) {
    unsigned u = __float_as_uint(f);
    return (unsigned short)((u + 0x7fffu + ((u >> 16) & 1u)) >> 16);
}

// ---------------------------------------------------------------------------
__global__ __launch_bounds__(256) void eeg_setup_kernel(
    const float* __restrict__ g1, const float* __restrict__ b1,
    const float* __restrict__ m1, const float* __restrict__ v1,
    const float* __restrict__ e1, const float* __restrict__ e2,
    const float* __restrict__ sw,
    const float* __restrict__ g2, const float* __restrict__ b2,
    const float* __restrict__ m2, const float* __restrict__ v2,
    const float* __restrict__ g3, const float* __restrict__ b3,
    const float* __restrict__ m3, const float* __restrict__ v3,
    const float* __restrict__ clsw, float* __restrict__ ws)
{
    const int tid = threadIdx.x;
    const int blk = blockIdx.x;

    if (blk < 48) {
        const int oc = blk;
        const int k = oc >> 4;          // hop: 0=identity, 1=A1, 2=A2
        __shared__ float A[64][65];
        __shared__ float rsl[64];
        __shared__ float swl[64];
        __shared__ float sred;

        if (k > 0) {
            const float* e = (k == 1) ? e1 : e2;
            for (int idx = tid; idx < 4096; idx += 256) {
                int i = idx >> 6, j = idx & 63;
                float v;
                if (i == j) v = 1.f;
                else {
                    int ii = i > j ? i : j, jj = i > j ? j : i;
                    v = e[ii * (ii - 1) / 2 + jj];
                }
                A[i][j] = v;
            }
        }
        if (tid < 64) swl[tid] = sw[oc * 64 + tid];
        __syncthreads();
        if (tid < 64) {
            if (k > 0) {
                float s = 0.f;
                for (int j = 0; j < 64; ++j) s += A[tid][j];
                rsl[tid] = 1.f / s;
            }
            float nv = swl[tid] * swl[tid];
            for (int off = 32; off; off >>= 1) nv += __shfl_down(nv, off);
            if (tid == 0) sred = nv;
        }
        __syncthreads();
        if (tid < 64) {
            const int j = tid;
            const float sn = fminf(1.f, 1.f / fmaxf(sqrtf(sred), 1e-7f));
            float w;
            if (k == 0) w = swl[j];
            else {
                float acc = 0.f;
                for (int c = 0; c < 64; ++c) acc += swl[c] * rsl[c] * A[c][j];
                w = acc;
            }
            w *= sn;
            const int f = (oc >> 1) & 7;
            const float a1 = g1[f] * rsqrtf(v1[f] + EPS_BN);
            const float a2 = g2[oc] * rsqrtf(v2[oc] + EPS_BN);
            const float wv = a2 * a1 * w;
            // bf16 hi/lo split, packed
            const unsigned short h = bf16_rne(wv);
            const float hf = __uint_as_float(((unsigned)h) << 16);
            const unsigned short lo = bf16_rne(wv - hf);
            ((unsigned*)ws)[WHL_OFF + oc * 64 + j] = (((unsigned)h) << 16) | lo;
            float S = w;
            for (int off = 32; off; off >>= 1) S += __shfl_down(S, off);
            if (tid == 0) {
                const float c1 = b1[f] - m1[f] * a1;
                const float c2 = b2[oc] - m2[oc] * a2;
                ws[BIAS_OFF + oc] = a2 * c1 * S + c2;
            }
        }
    } else {
        __shared__ float csc[4];
        if (tid < 16) {
            const float a3 = g3[tid] * rsqrtf(v3[tid] + EPS_BN);
            ws[A3_OFF + tid] = a3;
            ws[C3_OFF + tid] = b3[tid] - m3[tid] * a3;
        }
        {   // classifier renorm (maxnorm 0.25): row = wave
            const int row = tid >> 6, lane = tid & 63;
            float p = 0.f;
            if (row < 4)
                for (int idx = lane; idx < 240; idx += 64) {
                    float w = clsw[row * 240 + idx];
                    p += w * w;
                }
            for (int off = 32; off; off >>= 1) p += __shfl_down(p, off);
            if (row < 4 && lane == 0)
                csc[row] = fminf(1.f, 0.25f / fmaxf(sqrtf(p), 1e-7f));
        }
        __syncthreads();
        for (int idx = tid; idx < 960; idx += 256)
            ws[CLS_OFF + idx] = clsw[idx] * csc[idx / 240];
    }
}

// ---------------------------------------------------------------------------
// One rt body: load A frags (inside, pressure-bounded, L1-hot), 3 MFMAs.
#define RT_BODY(rt)                                                          \
    {                                                                        \
        const unsigned* ap = whl + (16 * (rt) + l15) * 64 + 32 * ks + 8 * lg;\
        const uint4 aw0 = *(const uint4*)ap;                                 \
        const uint4 aw1 = *(const uint4*)(ap + 4);                           \
        bf16x8 ah, al;                                                       \
        const unsigned* av0 = (const unsigned*)&aw0;                         \
        const unsigned* av1 = (const unsigned*)&aw1;                         \
        _Pragma("unroll")                                                    \
        for (int i = 0; i < 4; ++i) {                                        \
            ah[i] = (short)(av0[i] >> 16);                                   \
            al[i] = (short)(av0[i] & 0xffffu);                               \
            ah[i + 4] = (short)(av1[i] >> 16);                               \
            al[i + 4] = (short)(av1[i] & 0xffffu);                           \
        }                                                                    \
        acc[rt] = __builtin_amdgcn_mfma_f32_16x16x32_bf16(ah, bh, acc[rt], 0, 0, 0); \
        acc[rt] = __builtin_amdgcn_mfma_f32_16x16x32_bf16(ah, bl, acc[rt], 0, 0, 0); \
        acc[rt] = __builtin_amdgcn_mfma_f32_16x16x32_bf16(al, bh, acc[rt], 0, 0, 0); \
    }

// mix one 16-col tile (tilec = column tile index 0..11) into ps
__device__ __forceinline__ void mix_tile(
    const float* __restrict__ x, const unsigned* __restrict__ whl,
    float* __restrict__ smem, int b, int u0, int tilec, int l15, int lg)
{
    f32x4 acc[3];
#pragma unroll
    for (int rt = 0; rt < 3; ++rt) acc[rt] = (f32x4){0.f, 0.f, 0.f, 0.f};

    const int col = 16 * tilec + l15;
    const int u = u0 + col;
    const bool valid = (u >= 0) && (u < 1000);
    const float* xp = x + (size_t)b * 64000 + (valid ? u : 0);

#pragma unroll
    for (int ks = 0; ks < 2; ++ks) {
        float xf[8];
#pragma unroll
        for (int i = 0; i < 8; ++i) {
            const int j = 32 * ks + 8 * lg + i;
            xf[i] = valid ? xp[j * 1000] : 0.f;
        }
        bf16x8 bh, bl;
#pragma unroll
        for (int i = 0; i < 8; ++i) {
            const float f = xf[i];
            const unsigned short h = bf16_rne(f);
            const float hf = __uint_as_float(((unsigned)h) << 16);
            const unsigned short lo = bf16_rne(f - hf);
            bh[i] = (short)h;
            bl[i] = (short)lo;
        }
        RT_BODY(0)
        RT_BODY(1)
        RT_BODY(2)
    }
#pragma unroll
    for (int rt = 0; rt < 3; ++rt)
#pragma unroll
        for (int r = 0; r < 4; ++r)
            smem[S_PS + (16 * rt + 4 * lg + r) * 196 + col] = acc[rt][r];
}

__global__ __launch_bounds__(768) void eeg_stage1_kernel(
    const float* __restrict__ x, const float* __restrict__ tw,
    const float* __restrict__ wcon, float* __restrict__ out1)
{
    __shared__ float smem[S1_TOT];
    const int tid = threadIdx.x;
    const int lane = tid & 63;
    const int wv = tid >> 6;                 // wave 0..11 -> col-tile wv
    const int l15 = lane & 15;
    const int lg = lane >> 4;                // 0..3
    // XCD-aware swizzle (512 % 8 == 0, bijective)
    const int newid = (blockIdx.x & 7) * 64 + (blockIdx.x >> 3);
    const int b = newid >> 3;
    const int tile = newid & 7;              // 0..7
    const int o0 = tile * 16;
    const int u0 = 128 * tile - 32;

    // stage tw (stride 68, conflict-free) + bias
    if (tid < 512)
        smem[S_TW + (tid >> 6) * 68 + (tid & 63)] = tw[tid];
    if (tid < 48) smem[S_BIAS + tid] = wcon[BIAS_OFF + tid];

    const unsigned* whl = (const unsigned*)wcon;   // WHL_OFF = 0

    // mix: 12 waves x 12 col-tiles, single pass, no idle waves
    mix_tile(x, whl, smem, b, u0, wv, l15, lg);
    __syncthreads();   // ps complete (cross-wave) + tw/bias staged

    // ---- FIR(64) + bias + ELU + pool8: exactly 1 task per thread ----
    {
        const int oc = tid >> 4;             // 0..47
        const int o = tid & 15;              // 0..15
        const int oo = o0 + o;
        if (oo < 125) {
            const int f = (oc >> 1) & 7;
            const float* row = smem + S_PS + oc * 196 + o * 8;
            float win[72];
#pragma unroll
            for (int kk = 0; kk < 18; ++kk) {
                const float4 t = *(const float4*)(row + 4 * kk);
                win[4 * kk + 0] = t.x; win[4 * kk + 1] = t.y;
                win[4 * kk + 2] = t.z; win[4 * kk + 3] = t.w;
            }
            const float bs = smem[S_BIAS + oc];
            const float* twf = smem + S_TW + f * 68;
            float accv[8];
#pragma unroll
            for (int r = 0; r < 8; ++r) accv[r] = bs;
#pragma unroll
            for (int q0 = 0; q0 < 64; q0 += 8) {
                float tws[8];
                const float4 ta = *(const float4*)(twf + q0);
                const float4 tb = *(const float4*)(twf + q0 + 4);
                tws[0] = ta.x; tws[1] = ta.y; tws[2] = ta.z; tws[3] = ta.w;
                tws[4] = tb.x; tws[5] = tb.y; tws[6] = tb.z; tws[7] = tb.w;
#pragma unroll
                for (int q = 0; q < 8; ++q) {
#pragma unroll
                    for (int r = 0; r < 8; ++r)
                        accv[r] += tws[q] * win[q0 + q + r];
                }
            }
            float s = 0.f;
#pragma unroll
            for (int r = 0; r < 8; ++r) {
                const float v = accv[r];
                s += (v > 0.f) ? v : expm1f(v);
            }
            out1[((size_t)b * 48 + oc) * 125 + oo] = s * 0.125f;
        }
    }
}

// ---------------------------------------------------------------------------
// Stage 2: per batch, 512 threads. dw conv(16,pad8) -> pw 48->16 -> BN3+ELU
// -> pool8 -> classifier. 64 blocks, float4 LDS staging.
// ---------------------------------------------------------------------------
#define SB_P1   0        // [48][125]  (reused for QQ [16][126])
#define SB_DWO  6000     // [48][126]  (reused for pooled [16][15])
#define SB_DWL  12048    // [48][16]
#define SB_PWL  12816    // [16][48]
#define SB_CLS  13584    // [4][240]
#define SB_A3   14544    // [16]
#define SB_C3   14560    // [16]
#define SB_TOT  14576

__global__ __launch_bounds__(512) void eeg_stage2_kernel(
    const float* __restrict__ ws, const float* __restrict__ dww,
    const float* __restrict__ pww, const float* __restrict__ clsb,
    float* __restrict__ out)
{
    __shared__ float sb[SB_TOT];
    const int tid = threadIdx.x;
    const int b = blockIdx.x;
    const float* o1 = ws + OUT1_OFF + (size_t)b * 6000;

    for (int i = tid; i < 1500; i += 512)
        ((float4*)(sb + SB_P1))[i] = ((const float4*)o1)[i];
    if (tid < 192) ((float4*)(sb + SB_DWL))[tid] = ((const float4*)dww)[tid];
    if (tid < 192) ((float4*)(sb + SB_PWL))[tid] = ((const float4*)pww)[tid];
    if (tid < 240) ((float4*)(sb + SB_CLS))[tid] = ((const float4*)(ws + CLS_OFF))[tid];
    if (tid < 16) { sb[SB_A3 + tid] = ws[A3_OFF + tid]; sb[SB_C3 + tid] = ws[C3_OFF + tid]; }
    __syncthreads();

    // depthwise conv: K=16, pad 8, T 125 -> 126
    for (int idx = tid; idx < 48 * 126; idx += 512) {
        int ci = idx / 126, t = idx - ci * 126;
        float acc = 0.f;
#pragma unroll
        for (int r = 0; r < 16; ++r) {
            int tt = t - 8 + r;
            float xv = (tt >= 0 && tt < 125) ? sb[SB_P1 + ci * 125 + tt] : 0.f;
            acc += sb[SB_DWL + ci * 16 + r] * xv;
        }
        sb[SB_DWO + idx] = acc;
    }
    __syncthreads();
    // pointwise 48->16 + BN3 + ELU  (overwrites P1 region, disjoint from DWO)
    for (int idx = tid; idx < 16 * 126; idx += 512) {
        int co = idx / 126, t = idx - co * 126;
        float acc = 0.f;
#pragma unroll
        for (int ci = 0; ci < 48; ++ci)
            acc += sb[SB_PWL + co * 48 + ci] * sb[SB_DWO + ci * 126 + t];
        float v = sb[SB_A3 + co] * acc + sb[SB_C3 + co];
        sb[SB_P1 + idx] = (v > 0.f) ? v : expm1f(v);
    }
    __syncthreads();
    // pool8: 126 -> 15 (overwrites DWO region)
    if (tid < 240) {
        int co = tid / 15, v = tid - co * 15;
        float s = 0.f;
#pragma unroll
        for (int r = 0; r < 8; ++r) s += sb[SB_P1 + co * 126 + v * 8 + r];
        sb[SB_DWO + tid] = s * 0.125f;
    }
    __syncthreads();
    // classifier: wave w (<4) -> class w, 64-lane reduce over 240
    {
        const int wv = tid >> 6, lane = tid & 63;
        if (wv < 4) {
            float p = 0.f;
            for (int j2 = lane; j2 < 240; j2 += 64)
                p += sb[SB_CLS + wv * 240 + j2] * sb[SB_DWO + j2];
            for (int off = 32; off; off >>= 1) p += __shfl_down(p, off);
            if (lane == 0) out[(size_t)b * 4 + wv] = p + clsb[wv];
        }
    }
}

extern "C" void kernel_launch(void* const* d_in, const int* in_sizes, int n_in,
                              void* d_out, int out_size, void* d_ws, size_t ws_size,
                              hipStream_t stream) {
    const float* x    = (const float*)d_in[0];
    const float* tw   = (const float*)d_in[1];
    const float* g1   = (const float*)d_in[2];
    const float* b1   = (const float*)d_in[3];
    const float* m1   = (const float*)d_in[4];
    const float* v1   = (const float*)d_in[5];
    const float* e1   = (const float*)d_in[6];
    const float* e2   = (const float*)d_in[7];
    const float* sw   = (const float*)d_in[8];
    const float* g2   = (const float*)d_in[9];
    const float* b2   = (const float*)d_in[10];
    const float* m2   = (const float*)d_in[11];
    const float* v2   = (const float*)d_in[12];
    const float* dww  = (const float*)d_in[13];
    const float* pww  = (const float*)d_in[14];
    const float* g3   = (const float*)d_in[15];
    const float* b3   = (const float*)d_in[16];
    const float* m3   = (const float*)d_in[17];
    const float* v3   = (const float*)d_in[18];
    const float* clsw = (const float*)d_in[19];
    const float* clsb = (const float*)d_in[20];
    float* ws = (float*)d_ws;
    float* out = (float*)d_out;

    eeg_setup_kernel<<<49, 256, 0, stream>>>(g1, b1, m1, v1, e1, e2, sw,
                                             g2, b2, m2, v2, g3, b3, m3, v3,
                                             clsw, ws);
    eeg_stage1_kernel<<<512, 768, 0, stream>>>(x, tw, ws, ws + OUT1_OFF);
    eeg_stage2_kernel<<<64, 512, 0, stream>>>(ws, dww, pww, clsb, out);
}

// Round 25
// 39.550 us; speedup vs baseline: 1.4834x; 1.0374x over previous
//
#include <hip/hip_runtime.h>
#include <math.h>

// ---------------------------------------------------------------------------
// EEGGENET fused implementation (round 25 = r22, the measured optimum).
// Shapes: B=64, C=64, T=1000, F1=8, D=2, F2=16, KLEN=64, NCLS=4.
//
// Algebra: graph conv + spatial conv + BN1 + BN2 fold into Wf[48][64]; channel
// contraction commutes with the temporal conv. Mix P[48][192] = W x X on
// matrix cores via bf16 hi/lo split (absmax 2.4e-7 verified; 64-VGPR fit,
// no spill). tile = 16 pool outputs (192-col window, 12 col-tiles), 512
// blocks x 512 threads = 2 blocks/CU. Mix pass A = 8 waves x tiles 0-7;
// pass B = waves 0-3 x tiles 8-11. FIR: 768 tasks over 512 threads.
// Design-space scan (r21-r24): tile 8/16/32, 8/12/16 waves, 1/2/4 blk/CU ->
// this config is the minimum (39.8us); r23 (1 blk/CU) and r24 (12 waves)
// both worse. Remaining gap to ~10us arithmetic floor is barrier/latency
// structure, not a HW roofline (HBM ~7%, MfmaUtil ~2%).
// ---------------------------------------------------------------------------

#define EPS_BN 1e-3f

// ws layout (floats / u32)
#define WHL_OFF  0        // u32[48 oc][64 j]: (bf16hi<<16)|bf16lo of folded W
#define BIAS_OFF 3072     // bias[48]
#define A3_OFF   3120     // a3[16]
#define C3_OFF   3136     // c3[16]
#define CLS_OFF  3152     // renormed cls_w [4][240]
#define OUT1_OFF 4176     // pooled stage-1 output [64][48][125]

// stage1 smem (floats): 10000 = 40000 B; 512 thr -> 2 blocks/CU
#define S_PS   0          // ps[48][196]
#define S_TW   9408       // twp[8 f][68]
#define S_BIAS 9952       // [48]
#define S1_TOT 10000

typedef short bf16x8 __attribute__((ext_vector_type(8)));
typedef float f32x4 __attribute__((ext_vector_type(4)));

__device__ __forceinline__ unsigned short bf16_rne(float f) {
    unsigned u = __float_as_uint(f);
    return (unsigned short)((u + 0x7fffu + ((u >> 16) & 1u)) >> 16);
}

// ---------------------------------------------------------------------------
__global__ __launch_bounds__(256) void eeg_setup_kernel(
    const float* __restrict__ g1, const float* __restrict__ b1,
    const float* __restrict__ m1, const float* __restrict__ v1,
    const float* __restrict__ e1, const float* __restrict__ e2,
    const float* __restrict__ sw,
    const float* __restrict__ g2, const float* __restrict__ b2,
    const float* __restrict__ m2, const float* __restrict__ v2,
    const float* __restrict__ g3, const float* __restrict__ b3,
    const float* __restrict__ m3, const float* __restrict__ v3,
    const float* __restrict__ clsw, float* __restrict__ ws)
{
    const int tid = threadIdx.x;
    const int blk = blockIdx.x;

    if (blk < 48) {
        const int oc = blk;
        const int k = oc >> 4;          // hop: 0=identity, 1=A1, 2=A2
        __shared__ float A[64][65];
        __shared__ float rsl[64];
        __shared__ float swl[64];
        __shared__ float sred;

        if (k > 0) {
            const float* e = (k == 1) ? e1 : e2;
            for (int idx = tid; idx < 4096; idx += 256) {
                int i = idx >> 6, j = idx & 63;
                float v;
                if (i == j) v = 1.f;
                else {
                    int ii = i > j ? i : j, jj = i > j ? j : i;
                    v = e[ii * (ii - 1) / 2 + jj];
                }
                A[i][j] = v;
            }
        }
        if (tid < 64) swl[tid] = sw[oc * 64 + tid];
        __syncthreads();
        if (tid < 64) {
            if (k > 0) {
                float s = 0.f;
                for (int j = 0; j < 64; ++j) s += A[tid][j];
                rsl[tid] = 1.f / s;
            }
            float nv = swl[tid] * swl[tid];
            for (int off = 32; off; off >>= 1) nv += __shfl_down(nv, off);
            if (tid == 0) sred = nv;
        }
        __syncthreads();
        if (tid < 64) {
            const int j = tid;
            const float sn = fminf(1.f, 1.f / fmaxf(sqrtf(sred), 1e-7f));
            float w;
            if (k == 0) w = swl[j];
            else {
                float acc = 0.f;
                for (int c = 0; c < 64; ++c) acc += swl[c] * rsl[c] * A[c][j];
                w = acc;
            }
            w *= sn;
            const int f = (oc >> 1) & 7;
            const float a1 = g1[f] * rsqrtf(v1[f] + EPS_BN);
            const float a2 = g2[oc] * rsqrtf(v2[oc] + EPS_BN);
            const float wv = a2 * a1 * w;
            // bf16 hi/lo split, packed
            const unsigned short h = bf16_rne(wv);
            const float hf = __uint_as_float(((unsigned)h) << 16);
            const unsigned short lo = bf16_rne(wv - hf);
            ((unsigned*)ws)[WHL_OFF + oc * 64 + j] = (((unsigned)h) << 16) | lo;
            float S = w;
            for (int off = 32; off; off >>= 1) S += __shfl_down(S, off);
            if (tid == 0) {
                const float c1 = b1[f] - m1[f] * a1;
                const float c2 = b2[oc] - m2[oc] * a2;
                ws[BIAS_OFF + oc] = a2 * c1 * S + c2;
            }
        }
    } else {
        __shared__ float csc[4];
        if (tid < 16) {
            const float a3 = g3[tid] * rsqrtf(v3[tid] + EPS_BN);
            ws[A3_OFF + tid] = a3;
            ws[C3_OFF + tid] = b3[tid] - m3[tid] * a3;
        }
        {   // classifier renorm (maxnorm 0.25): row = wave
            const int row = tid >> 6, lane = tid & 63;
            float p = 0.f;
            if (row < 4)
                for (int idx = lane; idx < 240; idx += 64) {
                    float w = clsw[row * 240 + idx];
                    p += w * w;
                }
            for (int off = 32; off; off >>= 1) p += __shfl_down(p, off);
            if (row < 4 && lane == 0)
                csc[row] = fminf(1.f, 0.25f / fmaxf(sqrtf(p), 1e-7f));
        }
        __syncthreads();
        for (int idx = tid; idx < 960; idx += 256)
            ws[CLS_OFF + idx] = clsw[idx] * csc[idx / 240];
    }
}

// ---------------------------------------------------------------------------
// One rt body: load A frags (inside, pressure-bounded, L1-hot), 3 MFMAs.
#define RT_BODY(rt)                                                          \
    {                                                                        \
        const unsigned* ap = whl + (16 * (rt) + l15) * 64 + 32 * ks + 8 * lg;\
        const uint4 aw0 = *(const uint4*)ap;                                 \
        const uint4 aw1 = *(const uint4*)(ap + 4);                           \
        bf16x8 ah, al;                                                       \
        const unsigned* av0 = (const unsigned*)&aw0;                         \
        const unsigned* av1 = (const unsigned*)&aw1;                         \
        _Pragma("unroll")                                                    \
        for (int i = 0; i < 4; ++i) {                                        \
            ah[i] = (short)(av0[i] >> 16);                                   \
            al[i] = (short)(av0[i] & 0xffffu);                               \
            ah[i + 4] = (short)(av1[i] >> 16);                               \
            al[i + 4] = (short)(av1[i] & 0xffffu);                           \
        }                                                                    \
        acc[rt] = __builtin_amdgcn_mfma_f32_16x16x32_bf16(ah, bh, acc[rt], 0, 0, 0); \
        acc[rt] = __builtin_amdgcn_mfma_f32_16x16x32_bf16(ah, bl, acc[rt], 0, 0, 0); \
        acc[rt] = __builtin_amdgcn_mfma_f32_16x16x32_bf16(al, bh, acc[rt], 0, 0, 0); \
    }

// mix one 16-col tile (tilec = column tile index 0..11) into ps
__device__ __forceinline__ void mix_tile(
    const float* __restrict__ x, const unsigned* __restrict__ whl,
    float* __restrict__ smem, int b, int u0, int tilec, int l15, int lg)
{
    f32x4 acc[3];
#pragma unroll
    for (int rt = 0; rt < 3; ++rt) acc[rt] = (f32x4){0.f, 0.f, 0.f, 0.f};

    const int col = 16 * tilec + l15;
    const int u = u0 + col;
    const bool valid = (u >= 0) && (u < 1000);
    const float* xp = x + (size_t)b * 64000 + (valid ? u : 0);

#pragma unroll
    for (int ks = 0; ks < 2; ++ks) {
        float xf[8];
#pragma unroll
        for (int i = 0; i < 8; ++i) {
            const int j = 32 * ks + 8 * lg + i;
            xf[i] = valid ? xp[j * 1000] : 0.f;
        }
        bf16x8 bh, bl;
#pragma unroll
        for (int i = 0; i < 8; ++i) {
            const float f = xf[i];
            const unsigned short h = bf16_rne(f);
            const float hf = __uint_as_float(((unsigned)h) << 16);
            const unsigned short lo = bf16_rne(f - hf);
            bh[i] = (short)h;
            bl[i] = (short)lo;
        }
        RT_BODY(0)
        RT_BODY(1)
        RT_BODY(2)
    }
#pragma unroll
    for (int rt = 0; rt < 3; ++rt)
#pragma unroll
        for (int r = 0; r < 4; ++r)
            smem[S_PS + (16 * rt + 4 * lg + r) * 196 + col] = acc[rt][r];
}

__global__ __launch_bounds__(512) void eeg_stage1_kernel(
    const float* __restrict__ x, const float* __restrict__ tw,
    const float* __restrict__ wcon, float* __restrict__ out1)
{
    __shared__ float smem[S1_TOT];
    const int tid = threadIdx.x;
    const int lane = tid & 63;
    const int wv = tid >> 6;                 // wave 0..7
    const int l15 = lane & 15;
    const int lg = lane >> 4;                // 0..3
    // XCD-aware swizzle (512 % 8 == 0, bijective)
    const int newid = (blockIdx.x & 7) * 64 + (blockIdx.x >> 3);
    const int b = newid >> 3;
    const int tile = newid & 7;              // 0..7
    const int o0 = tile * 16;
    const int u0 = 128 * tile - 32;

    // stage tw (stride 68, conflict-free) + bias
    smem[S_TW + (tid >> 6) * 68 + (tid & 63)] = tw[tid];
    if (tid < 48) smem[S_BIAS + tid] = wcon[BIAS_OFF + tid];

    const unsigned* whl = (const unsigned*)wcon;   // WHL_OFF = 0

    // mix pass A: tiles 0..7 (all waves); pass B: tiles 8..11 (waves 0..3)
    mix_tile(x, whl, smem, b, u0, wv, l15, lg);
    if (wv < 4) mix_tile(x, whl, smem, b, u0, 8 + wv, l15, lg);
    __syncthreads();   // ps complete (cross-wave) + tw/bias staged

    // ---- FIR(64) + bias + ELU + pool8: 768 tasks over 512 threads ----
#pragma unroll
    for (int p = 0; p < 2; ++p) {
        const int task = p * 512 + tid;
        if (task < 768) {
            const int oc = task >> 4;
            const int o = task & 15;
            const int oo = o0 + o;
            if (oo < 125) {
                const int f = (oc >> 1) & 7;
                const float* row = smem + S_PS + oc * 196 + o * 8;
                float win[72];
#pragma unroll
                for (int kk = 0; kk < 18; ++kk) {
                    const float4 t = *(const float4*)(row + 4 * kk);
                    win[4 * kk + 0] = t.x; win[4 * kk + 1] = t.y;
                    win[4 * kk + 2] = t.z; win[4 * kk + 3] = t.w;
                }
                const float bs = smem[S_BIAS + oc];
                const float* twf = smem + S_TW + f * 68;
                float accv[8];
#pragma unroll
                for (int r = 0; r < 8; ++r) accv[r] = bs;
#pragma unroll
                for (int q0 = 0; q0 < 64; q0 += 8) {
                    float tws[8];
                    const float4 ta = *(const float4*)(twf + q0);
                    const float4 tb = *(const float4*)(twf + q0 + 4);
                    tws[0] = ta.x; tws[1] = ta.y; tws[2] = ta.z; tws[3] = ta.w;
                    tws[4] = tb.x; tws[5] = tb.y; tws[6] = tb.z; tws[7] = tb.w;
#pragma unroll
                    for (int q = 0; q < 8; ++q) {
#pragma unroll
                        for (int r = 0; r < 8; ++r)
                            accv[r] += tws[q] * win[q0 + q + r];
                    }
                }
                float s = 0.f;
#pragma unroll
                for (int r = 0; r < 8; ++r) {
                    const float v = accv[r];
                    s += (v > 0.f) ? v : expm1f(v);
                }
                out1[((size_t)b * 48 + oc) * 125 + oo] = s * 0.125f;
            }
        }
    }
}

// ---------------------------------------------------------------------------
// Stage 2: per batch, 512 threads. dw conv(16,pad8) -> pw 48->16 -> BN3+ELU
// -> pool8 -> classifier. 64 blocks, float4 LDS staging.
// ---------------------------------------------------------------------------
#define SB_P1   0        // [48][125]  (reused for QQ [16][126])
#define SB_DWO  6000     // [48][126]  (reused for pooled [16][15])
#define SB_DWL  12048    // [48][16]
#define SB_PWL  12816    // [16][48]
#define SB_CLS  13584    // [4][240]
#define SB_A3   14544    // [16]
#define SB_C3   14560    // [16]
#define SB_TOT  14576

__global__ __launch_bounds__(512) void eeg_stage2_kernel(
    const float* __restrict__ ws, const float* __restrict__ dww,
    const float* __restrict__ pww, const float* __restrict__ clsb,
    float* __restrict__ out)
{
    __shared__ float sb[SB_TOT];
    const int tid = threadIdx.x;
    const int b = blockIdx.x;
    const float* o1 = ws + OUT1_OFF + (size_t)b * 6000;

    for (int i = tid; i < 1500; i += 512)
        ((float4*)(sb + SB_P1))[i] = ((const float4*)o1)[i];
    if (tid < 192) ((float4*)(sb + SB_DWL))[tid] = ((const float4*)dww)[tid];
    if (tid < 192) ((float4*)(sb + SB_PWL))[tid] = ((const float4*)pww)[tid];
    if (tid < 240) ((float4*)(sb + SB_CLS))[tid] = ((const float4*)(ws + CLS_OFF))[tid];
    if (tid < 16) { sb[SB_A3 + tid] = ws[A3_OFF + tid]; sb[SB_C3 + tid] = ws[C3_OFF + tid]; }
    __syncthreads();

    // depthwise conv: K=16, pad 8, T 125 -> 126
    for (int idx = tid; idx < 48 * 126; idx += 512) {
        int ci = idx / 126, t = idx - ci * 126;
        float acc = 0.f;
#pragma unroll
        for (int r = 0; r < 16; ++r) {
            int tt = t - 8 + r;
            float xv = (tt >= 0 && tt < 125) ? sb[SB_P1 + ci * 125 + tt] : 0.f;
            acc += sb[SB_DWL + ci * 16 + r] * xv;
        }
        sb[SB_DWO + idx] = acc;
    }
    __syncthreads();
    // pointwise 48->16 + BN3 + ELU  (overwrites P1 region, disjoint from DWO)
    for (int idx = tid; idx < 16 * 126; idx += 512) {
        int co = idx / 126, t = idx - co * 126;
        float acc = 0.f;
#pragma unroll
        for (int ci = 0; ci < 48; ++ci)
            acc += sb[SB_PWL + co * 48 + ci] * sb[SB_DWO + ci * 126 + t];
        float v = sb[SB_A3 + co] * acc + sb[SB_C3 + co];
        sb[SB_P1 + idx] = (v > 0.f) ? v : expm1f(v);
    }
    __syncthreads();
    // pool8: 126 -> 15 (overwrites DWO region)
    if (tid < 240) {
        int co = tid / 15, v = tid - co * 15;
        float s = 0.f;
#pragma unroll
        for (int r = 0; r < 8; ++r) s += sb[SB_P1 + co * 126 + v * 8 + r];
        sb[SB_DWO + tid] = s * 0.125f;
    }
    __syncthreads();
    // classifier: wave w (<4) -> class w, 64-lane reduce over 240
    {
        const int wv = tid >> 6, lane = tid & 63;
        if (wv < 4) {
            float p = 0.f;
            for (int j2 = lane; j2 < 240; j2 += 64)
                p += sb[SB_CLS + wv * 240 + j2] * sb[SB_DWO + j2];
            for (int off = 32; off; off >>= 1) p += __shfl_down(p, off);
            if (lane == 0) out[(size_t)b * 4 + wv] = p + clsb[wv];
        }
    }
}

extern "C" void kernel_launch(void* const* d_in, const int* in_sizes, int n_in,
                              void* d_out, int out_size, void* d_ws, size_t ws_size,
                              hipStream_t stream) {
    const float* x    = (const float*)d_in[0];
    const float* tw   = (const float*)d_in[1];
    const float* g1   = (const float*)d_in[2];
    const float* b1   = (const float*)d_in[3];
    const float* m1   = (const float*)d_in[4];
    const float* v1   = (const float*)d_in[5];
    const float* e1   = (const float*)d_in[6];
    const float* e2   = (const float*)d_in[7];
    const float* sw   = (const float*)d_in[8];
    const float* g2   = (const float*)d_in[9];
    const float* b2   = (const float*)d_in[10];
    const float* m2   = (const float*)d_in[11];
    const float* v2   = (const float*)d_in[12];
    const float* dww  = (const float*)d_in[13];
    const float* pww  = (const float*)d_in[14];
    const float* g3   = (const float*)d_in[15];
    const float* b3   = (const float*)d_in[16];
    const float* m3   = (const float*)d_in[17];
    const float* v3   = (const float*)d_in[18];
    const float* clsw = (const float*)d_in[19];
    const float* clsb = (const float*)d_in[20];
    float* ws = (float*)d_ws;
    float* out = (float*)d_out;

    eeg_setup_kernel<<<49, 256, 0, stream>>>(g1, b1, m1, v1, e1, e2, sw,
                                             g2, b2, m2, v2, g3, b3, m3, v3,
                                             clsw, ws);
    eeg_stage1_kernel<<<512, 512, 0, stream>>>(x, tw, ws, ws + OUT1_OFF);
    eeg_stage2_kernel<<<64, 512, 0, stream>>>(ws, dww, pww, clsb, out);
}